// Round 5
// baseline (6931.047 us; speedup 1.0000x reference)
//
#include <hip/hip_runtime.h>

// LSTM B=1024 T=512 H=256 (input_size=1, output_size=1) on MI355X.
// R9: force the register budget. R8 post-mortem: __launch_bounds__ only
// CAPS VGPRs; for 1024-thr workgroups the backend's occupancy heuristic
// targets 8 waves/EU and allocates 64 VGPRs ((512,2)->128, (1024,*)->64
// across R4/R5/R8), spilling the ~126-reg working set to scratch
// (WRITE 31.5MB, FETCH 92MB, MfmaUtil 1.6%). Fix: explicit
// amdgpu_waves_per_eu(4,4) + flat_work_group_size(1024,1024) -> exactly
// 4 waves/EU -> 128-reg budget, allocator must not shrink for occupancy.
// Structure (unchanged from R8): 64 blocks x 1024 thr (16 waves). Wave w
// owns hidden cols [16w,16w+16) and all 4 gate tiles:
//   i (Tn=w): register-resident (32 VGPR)
//   f,g,o (Tn=16+w,32+w,48+w): streamed from L2 via three rotating 16-reg
//     quarter-buffers, 4-kc prefetch distance; kc>=4 reloads are next-step
//     tiles in flight across the barrier. Unique stream set = 384KB,
//     L2/L3-resident (8 blocks/XCD share the same lines).
// LDS = 17KB h double-buffer only (64 b128 afrag reads + h writes/step).
// Per-step model @4 waves/SIMD: max(LDS ~800, L2 ~1700, VALU ~1600,
// MFMA 640) overlapped -> ~0.9-1.2us/step.

#define HID 256
#define TT 512
#define NBLK 64
#define THREADS 1024
#define HPAD 264   // 256 cols + 8 pad (ushort units)

typedef float v4f __attribute__((ext_vector_type(4)));
typedef unsigned int v4u __attribute__((ext_vector_type(4)));
typedef __bf16 v8bf __attribute__((ext_vector_type(8)));

__device__ __forceinline__ unsigned short f2bf(float f) {
    unsigned int u = __builtin_bit_cast(unsigned int, f);
    u += 0x7fffu + ((u >> 16) & 1u);   // RNE
    return (unsigned short)(u >> 16);
}
__device__ __forceinline__ float bf2f(unsigned short s) {
    unsigned int u = ((unsigned int)s) << 16;
    return __builtin_bit_cast(float, u);
}
__device__ __forceinline__ float fsigmoid(float x) {
    float e = exp2f(x * -1.44269504f);
    return __builtin_amdgcn_rcpf(1.0f + e);
}
__device__ __forceinline__ float ftanh(float x) {
    float e = exp2f(x * 2.88539008f);
    return 1.0f - 2.0f * __builtin_amdgcn_rcpf(1.0f + e);
}

// W_hh fp32 [1024][256] -> bf16 fragment order:
// Wbf[((Tn*8+kc)*64+lane)*8 + j] = bf16(W_hh[16*Tn+(lane&15)][32*kc+(lane>>4)*8+j])
__global__ void wconv_kernel(const float* __restrict__ Whh,
                             unsigned short* __restrict__ Wbf) {
    int tid = blockIdx.x * blockDim.x + threadIdx.x;   // 0..32767
    int lane = tid & 63;
    int frag = tid >> 6;
    int Tn = frag >> 3;
    int kc = frag & 7;
    int n  = Tn * 16 + (lane & 15);
    int kb = kc * 32 + (lane >> 4) * 8;
    const float* src = Whh + (size_t)n * HID + kb;
    unsigned short* dst = Wbf + (size_t)tid * 8;
#pragma unroll
    for (int j = 0; j < 8; ++j) dst[j] = f2bf(src[j]);
}

#define MFMA_BF16 __builtin_amdgcn_mfma_f32_16x16x32_bf16

__global__
__attribute__((amdgpu_flat_work_group_size(1024, 1024), amdgpu_waves_per_eu(4, 4)))
void lstm_kernel(const float* __restrict__ x,
                 const float* __restrict__ W_ih,
                 const float* __restrict__ b_ih,
                 const float* __restrict__ b_hh,
                 const float* __restrict__ W_lin,
                 const float* __restrict__ b_lin,
                 const unsigned short* __restrict__ Wbf,
                 float* __restrict__ out) {
    __shared__ __align__(16) unsigned short hbuf[2][16 * HPAD];   // 16.9 KB

    const int tid  = threadIdx.x;
    const int lane = tid & 63;
    const int w    = tid >> 6;      // wave 0..15; owns cols [16w, 16w+16)
    const int l4   = lane & 15;
    const int quad = lane >> 4;
    const int r0   = blockIdx.x * 16;
    const int col  = 16 * w + l4;   // this thread's hidden column

    // i-gate tile register-resident (Tn = w): 32 VGPR
    v8bf wi[8];
#pragma unroll
    for (int kc = 0; kc < 8; ++kc)
        wi[kc] = __builtin_bit_cast(v8bf,
            *((const v4u*)Wbf + ((size_t)(w * 8 + kc)) * 64 + lane));

    // stream bases for f, g, o (v4u-indexed; tiles 16+w, 32+w, 48+w)
    const v4u* fptr = (const v4u*)Wbf + ((size_t)(16 + w) * 8) * 64 + lane;
    const v4u* gptr = fptr + (size_t)16 * 8 * 64;   // +16 tiles
    const v4u* optr = fptr + (size_t)32 * 8 * 64;   // +32 tiles

    // rotating quarter buffers; prologue holds kc 0..3
    v4u fb[4], gb[4], ob[4];
#pragma unroll
    for (int j = 0; j < 4; ++j) {
        fb[j] = fptr[j * 64];
        gb[j] = gptr[j * 64];
        ob[j] = optr[j * 64];
    }

    // per-thread gate constants
    const float cwi = W_ih[col],       cbi = b_ih[col]       + b_hh[col];
    const float cwf = W_ih[256 + col], cbf = b_ih[256 + col] + b_hh[256 + col];
    const float cwg = W_ih[512 + col], cbg = b_ih[512 + col] + b_hh[512 + col];
    const float cwo = W_ih[768 + col], cbo = b_ih[768 + col] + b_hh[768 + col];

    for (int i = tid; i < 16 * HPAD; i += THREADS) hbuf[0][i] = 0;

    float xv[4];
#pragma unroll
    for (int r = 0; r < 4; ++r) xv[r] = x[(size_t)(r0 + quad * 4 + r) * TT];

    __syncthreads();

    float c_st[4] = {0.f, 0.f, 0.f, 0.f};
    int cur = 0;

    for (int t = 0; t < TT; ++t) {
        const unsigned short* hrow = hbuf[cur] + l4 * HPAD + quad * 8;
        unsigned short* hn = hbuf[cur ^ 1];

        v4f ai, af, ag, ao;
#pragma unroll
        for (int r = 0; r < 4; ++r) {
            ai[r] = xv[r] * cwi + cbi;
            af[r] = xv[r] * cwf + cbf;
            ag[r] = xv[r] * cwg + cbg;
            ao[r] = xv[r] * cwo + cbo;
        }

#pragma unroll
        for (int kc = 0; kc < 8; ++kc) {
            v8bf a = __builtin_bit_cast(v8bf, *(const v4u*)(hrow + kc * 32));
            ai = MFMA_BF16(a, wi[kc], ai, 0, 0, 0);
            af = MFMA_BF16(a, __builtin_bit_cast(v8bf, fb[kc & 3]), af, 0, 0, 0);
            ag = MFMA_BF16(a, __builtin_bit_cast(v8bf, gb[kc & 3]), ag, 0, 0, 0);
            ao = MFMA_BF16(a, __builtin_bit_cast(v8bf, ob[kc & 3]), ao, 0, 0, 0);
            // reload just-consumed quarter: kc<4 -> kc+4 (later this step),
            // kc>=4 -> kc-4 (next step; stays in flight across the barrier)
            fb[kc & 3] = fptr[((kc + 4) & 7) * 64];
            gb[kc & 3] = gptr[((kc + 4) & 7) * 64];
            ob[kc & 3] = optr[((kc + 4) & 7) * 64];
        }

#pragma unroll
        for (int r = 0; r < 4; ++r) {
            float gi = fsigmoid(ai[r]);
            float gf = fsigmoid(af[r]);
            float gg = ftanh(ag[r]);
            float go = fsigmoid(ao[r]);
            float cn = gf * c_st[r] + gi * gg;
            c_st[r] = cn;
            hn[(quad * 4 + r) * HPAD + col] = f2bf(go * ftanh(cn));
        }

        // x prefetch for t+1 (wraps harmlessly at the end)
        {
            int tn = (t + 1) & (TT - 1);
#pragma unroll
            for (int r = 0; r < 4; ++r)
                xv[r] = x[(size_t)(r0 + quad * 4 + r) * TT + tn];
        }

        __syncthreads();
        cur ^= 1;
    }

    // Epilogue: wave w reduces batch row w: out[r0+w] = h . W_lin + b_lin
    float p = 0.f;
#pragma unroll
    for (int j = 0; j < 4; ++j) {
        int c = lane * 4 + j;
        p += bf2f(hbuf[cur][w * HPAD + c]) * W_lin[c];
    }
#pragma unroll
    for (int off = 32; off; off >>= 1) p += __shfl_down(p, off);
    if (lane == 0) out[r0 + w] = p + b_lin[0];
}

extern "C" void kernel_launch(void* const* d_in, const int* in_sizes, int n_in,
                              void* d_out, int out_size, void* d_ws, size_t ws_size,
                              hipStream_t stream) {
    const float* x     = (const float*)d_in[0];
    const float* W_ih  = (const float*)d_in[1];
    const float* W_hh  = (const float*)d_in[2];
    const float* b_ih  = (const float*)d_in[3];
    const float* b_hh  = (const float*)d_in[4];
    const float* W_lin = (const float*)d_in[5];
    const float* b_lin = (const float*)d_in[6];
    unsigned short* Wbf = (unsigned short*)d_ws;   // 512 KB

    wconv_kernel<<<128, 256, 0, stream>>>(W_hh, Wbf);
    lstm_kernel<<<NBLK, THREADS, 0, stream>>>(x, W_ih, b_ih, b_hh, W_lin, b_lin,
                                              Wbf, (float*)d_out);
}

// Round 6
// 1814.276 us; speedup vs baseline: 3.8203x; 3.8203x over previous
//
#include <hip/hip_runtime.h>

// LSTM B=1024 T=512 H=256 (input_size=1, output_size=1) on MI355X.
// R10: use the full register file. R9 post-mortem: 1024-thr configs are
// allocator-capped at 64 VGPR (3 attempts) -> dead. R4 (1583us, best) used
// (512,2) which CAPPED at 128 VGPR -- pointless, since grid=64 means only
// 1 block/CU is ever resident. At (512,1) the allocator uses what's needed
// (R6:68, R7:108) up to 256. So: keep R4's shape (64 blk x 512 thr,
// 8 waves/CU, 2/SIMD) and spend the full budget:
//   i,f,o gates, both S: register-resident  (6 tiles x 32 = 192 VGPR)
//   g gate, both S:      LDS-resident       (16 tiles = 128 KB)
// -> o-gate L2 stream GONE (R4's main latency leak), INITG's per-step
// scalar gw/gb LDS reads (740cy/CU) -> 2x b128 cpk reads (~200cy),
// consumed AFTER the MFMAs (acc starts at 0, xg added in GATES) to keep
// peak pressure ~256. kc-major inner loop: afrag read + 2 g reads + 8
// MFMAs per kc (afrag not a 32-reg persistent array).
// Per-step/CU model: LDS (64+128+16)x12 + 400 writes ~ 2900cy; VALU ~1500,
// MFMA 640 on other pipes; no L2 stalls -> ~3800-4500 cy/step.

#define HID 256
#define TT 512
#define NBLK 64
#define THREADS 512
#define HPAD 264   // 256 cols + 8 pad (ushort units)

typedef float v4f __attribute__((ext_vector_type(4)));
typedef unsigned int v4u __attribute__((ext_vector_type(4)));
typedef __bf16 v8bf __attribute__((ext_vector_type(8)));

__device__ __forceinline__ unsigned short f2bf(float f) {
    unsigned int u = __builtin_bit_cast(unsigned int, f);
    u += 0x7fffu + ((u >> 16) & 1u);   // RNE
    return (unsigned short)(u >> 16);
}
__device__ __forceinline__ float bf2f(unsigned short s) {
    unsigned int u = ((unsigned int)s) << 16;
    return __builtin_bit_cast(float, u);
}
__device__ __forceinline__ float fsigmoid(float x) {
    float e = exp2f(x * -1.44269504f);
    return __builtin_amdgcn_rcpf(1.0f + e);
}
__device__ __forceinline__ float ftanh(float x) {
    float e = exp2f(x * 2.88539008f);
    return 1.0f - 2.0f * __builtin_amdgcn_rcpf(1.0f + e);
}

// W_hh fp32 [1024][256] -> bf16 fragment order:
// Wbf[((Tn*8+kc)*64+lane)*8 + j] = bf16(W_hh[16*Tn+(lane&15)][32*kc+(lane>>4)*8+j])
__global__ void wconv_kernel(const float* __restrict__ Whh,
                             unsigned short* __restrict__ Wbf) {
    int tid = blockIdx.x * blockDim.x + threadIdx.x;   // 0..32767
    int lane = tid & 63;
    int frag = tid >> 6;
    int Tn = frag >> 3;
    int kc = frag & 7;
    int n  = Tn * 16 + (lane & 15);
    int kb = kc * 32 + (lane >> 4) * 8;
    const float* src = Whh + (size_t)n * HID + kb;
    unsigned short* dst = Wbf + (size_t)tid * 8;
#pragma unroll
    for (int j = 0; j < 8; ++j) dst[j] = f2bf(src[j]);
}

#define MFMA_BF16 __builtin_amdgcn_mfma_f32_16x16x32_bf16

__global__ __launch_bounds__(THREADS, 1)
void lstm_kernel(const float* __restrict__ x,
                 const float* __restrict__ W_ih,
                 const float* __restrict__ b_ih,
                 const float* __restrict__ b_hh,
                 const float* __restrict__ W_lin,
                 const float* __restrict__ b_lin,
                 const unsigned short* __restrict__ Wbf,
                 float* __restrict__ out) {
    __shared__ __align__(16) unsigned short Wlds[16 * 8 * 64 * 8];   // 128 KB (g)
    __shared__ __align__(16) unsigned short hbuf[2][16 * HPAD];      // 16.9 KB
    __shared__ __align__(16) float cpk[2048];                        // 8 KB consts
    __shared__ float part[THREADS];                                  // 2 KB

    const int tid  = threadIdx.x;
    const int lane = tid & 63;
    const int w    = tid >> 6;      // wave 0..7
    const int l4   = lane & 15;
    const int quad = lane >> 4;
    const int r0   = blockIdx.x * 16;

    // stage g-gate tiles for both S: slot = w*2+S <- Tn = 32 + w + 8*S
#pragma unroll
    for (int S = 0; S < 2; ++S) {
        int Tn = 32 + w + 8 * S;
        int slot = w * 2 + S;
#pragma unroll
        for (int kc = 0; kc < 8; ++kc)
            *(v4u*)(Wlds + ((size_t)((slot * 8 + kc) * 64 + lane)) * 8) =
                *(const v4u*)(Wbf + ((size_t)((Tn * 8 + kc) * 64 + lane)) * 8);
    }

    // packed gate consts: cpk[col*8 + {0..3}] = W_ih[g*256+col],
    //                     cpk[col*8 + {4..7}] = b_ih[g*256+col]+b_hh[g*256+col]
    for (int i = tid; i < 2048; i += THREADS) {
        int col = i >> 3, j = i & 7;
        cpk[i] = (j < 4) ? W_ih[j * 256 + col]
                         : b_ih[(j - 4) * 256 + col] + b_hh[(j - 4) * 256 + col];
    }

    // h(0) = 0
    for (int i = tid; i < 16 * HPAD; i += THREADS) hbuf[0][i] = 0;

    // register-resident i,f,o tiles, both S: wr[S][G][kc], G: 0=i,1=f,2=o
    v8bf wr[2][3][8];
#pragma unroll
    for (int S = 0; S < 2; ++S)
#pragma unroll
        for (int G = 0; G < 3; ++G) {
            int gc = (G == 2) ? 3 : G;
            int Tn = 16 * gc + w + 8 * S;
#pragma unroll
            for (int kc = 0; kc < 8; ++kc)
                wr[S][G][kc] = __builtin_bit_cast(v8bf, *(const v4u*)(Wbf +
                    ((size_t)(Tn * 8 + kc) * 64 + lane) * 8));
        }

    float xv[4];
#pragma unroll
    for (int r = 0; r < 4; ++r) xv[r] = x[(size_t)(r0 + quad * 4 + r) * TT];

    __syncthreads();

    float c_st[8];
#pragma unroll
    for (int i = 0; i < 8; ++i) c_st[i] = 0.0f;
    int cur = 0;

    for (int t = 0; t < TT; ++t) {
        const unsigned short* hrow = hbuf[cur] + l4 * HPAD + quad * 8;
        unsigned short* hn = hbuf[cur ^ 1];

        v4f ai0 = 0.f, af0 = 0.f, ao0 = 0.f, ag0 = 0.f;
        v4f ai1 = 0.f, af1 = 0.f, ao1 = 0.f, ag1 = 0.f;

#pragma unroll
        for (int kc = 0; kc < 8; ++kc) {
            v8bf a = __builtin_bit_cast(v8bf, *(const v4u*)(hrow + kc * 32));
            v8bf g0 = __builtin_bit_cast(v8bf, *(const v4u*)(Wlds +
                        ((size_t)(((w * 2 + 0) * 8 + kc) * 64 + lane)) * 8));
            v8bf g1 = __builtin_bit_cast(v8bf, *(const v4u*)(Wlds +
                        ((size_t)(((w * 2 + 1) * 8 + kc) * 64 + lane)) * 8));
            ai0 = MFMA_BF16(a, wr[0][0][kc], ai0, 0, 0, 0);
            af0 = MFMA_BF16(a, wr[0][1][kc], af0, 0, 0, 0);
            ao0 = MFMA_BF16(a, wr[0][2][kc], ao0, 0, 0, 0);
            ag0 = MFMA_BF16(a, g0, ag0, 0, 0, 0);
            ai1 = MFMA_BF16(a, wr[1][0][kc], ai1, 0, 0, 0);
            af1 = MFMA_BF16(a, wr[1][1][kc], af1, 0, 0, 0);
            ao1 = MFMA_BF16(a, wr[1][2][kc], ao1, 0, 0, 0);
            ag1 = MFMA_BF16(a, g1, ag1, 0, 0, 0);
        }

        // GATES S=0 (xg added here; acc started at 0)
        {
            int colS = 16 * w + l4;
            v4f w4 = *(const v4f*)(cpk + colS * 8);
            v4f b4 = *(const v4f*)(cpk + colS * 8 + 4);
#pragma unroll
            for (int r = 0; r < 4; ++r) {
                float gi = fsigmoid(ai0[r] + xv[r] * w4[0] + b4[0]);
                float gf = fsigmoid(af0[r] + xv[r] * w4[1] + b4[1]);
                float gg = ftanh(ag0[r] + xv[r] * w4[2] + b4[2]);
                float go = fsigmoid(ao0[r] + xv[r] * w4[3] + b4[3]);
                float cn = gf * c_st[r] + gi * gg;
                c_st[r] = cn;
                hn[(quad * 4 + r) * HPAD + colS] = f2bf(go * ftanh(cn));
            }
        }
        // GATES S=1
        {
            int colS = 16 * (w + 8) + l4;
            v4f w4 = *(const v4f*)(cpk + colS * 8);
            v4f b4 = *(const v4f*)(cpk + colS * 8 + 4);
#pragma unroll
            for (int r = 0; r < 4; ++r) {
                float gi = fsigmoid(ai1[r] + xv[r] * w4[0] + b4[0]);
                float gf = fsigmoid(af1[r] + xv[r] * w4[1] + b4[1]);
                float gg = ftanh(ag1[r] + xv[r] * w4[2] + b4[2]);
                float go = fsigmoid(ao1[r] + xv[r] * w4[3] + b4[3]);
                float cn = gf * c_st[4 + r] + gi * gg;
                c_st[4 + r] = cn;
                hn[(quad * 4 + r) * HPAD + colS] = f2bf(go * ftanh(cn));
            }
        }

        // x prefetch for t+1 (wraps harmlessly)
        {
            int tn = (t + 1) & (TT - 1);
#pragma unroll
            for (int r = 0; r < 4; ++r)
                xv[r] = x[(size_t)(r0 + quad * 4 + r) * TT + tn];
        }

        __syncthreads();
        cur ^= 1;
    }

    // Epilogue: out[b] = h_final . W_lin + b_lin
    {
        int rrow = tid >> 5, s5 = tid & 31;
        float p = 0.0f;
#pragma unroll
        for (int jj = 0; jj < 8; ++jj) {
            int j = s5 * 8 + jj;
            p += bf2f(hbuf[cur][rrow * HPAD + j]) * W_lin[j];
        }
        part[tid] = p;
    }
    __syncthreads();
    if (tid < 16) {
        float sum = 0.0f;
#pragma unroll
        for (int s = 0; s < 32; ++s) sum += part[tid * 32 + s];
        out[r0 + tid] = sum + b_lin[0];
    }
}

extern "C" void kernel_launch(void* const* d_in, const int* in_sizes, int n_in,
                              void* d_out, int out_size, void* d_ws, size_t ws_size,
                              hipStream_t stream) {
    const float* x     = (const float*)d_in[0];
    const float* W_ih  = (const float*)d_in[1];
    const float* W_hh  = (const float*)d_in[2];
    const float* b_ih  = (const float*)d_in[3];
    const float* b_hh  = (const float*)d_in[4];
    const float* W_lin = (const float*)d_in[5];
    const float* b_lin = (const float*)d_in[6];
    unsigned short* Wbf = (unsigned short*)d_ws;   // 512 KB

    wconv_kernel<<<128, 256, 0, stream>>>(W_hh, Wbf);
    lstm_kernel<<<NBLK, THREADS, 0, stream>>>(x, W_ih, b_ih, b_hh, W_lin, b_lin,
                                              Wbf, (float*)d_out);
}